// Round 2
// baseline (80.613 us; speedup 1.0000x reference)
//
#include <hip/hip_runtime.h>
#include <hip/hip_bf16.h>
#include <math.h>

// ProbaV cPSNR:  loss(u,v) = E[d^2] - (E[d])^2,  d = ct - pm_window(u,v)
// Decomposition: S1(u,v) = T1 - W1(u,v);  S2(u,v) = T2 - 2*CC(u,v) + W2(u,v)
//   T1,T2   : sum ct, sum ct^2                (ct = target*mask, inner 378x378 @ +3)
//   CC(u,v) : sum ct[r][c] * pm[r+u][c+v]     (pm = predict*mask, full 384x384)
//   W1,W2   : window sums of pm, pm^2 over rows [u,u+378) x cols [v,v+378)
// W via inclusion-exclusion over universe rows 0..382 x cols 0..383:
//   W = Total - BR(u) - BC(v) + X(u,v)
//   BR from full-row sums of rows {0..4, 378..382}   (10 rows)
//   BC from full-col sums (rows 0..382) of cols {0..4, 378..383} (11 cols)
//   X  from the 10x11 corner table.

#define NIMG 32
#define IMGSZ (384 * 384)
#define NRT 126              // row tiles (3 ct rows each; 126*3 = 378 exact)
#define NSG 48               // col segments (8 cols)
#define NTILES (NIMG * NRT * NSG)   // 193536
#define NBLK (NTILES / 256)          // 756
#define NM 40                // per-block main partials: cc[36], t1, t2, tot1, tot2
#define NE 262               // per-image edge partials

// ---------------- main kernel: CC + T1/T2 + Total(pm,pm^2) ----------------
__global__ __launch_bounds__(256, 3) void probav_cc_kernel(
    const float* __restrict__ predict,
    const float* __restrict__ target,
    const float* __restrict__ mask,
    float* __restrict__ mpart /* [NBLK][NM] */) {

  const int tid = blockIdx.x * 256 + threadIdx.x;
  const int img = tid / (NRT * NSG);
  const int rem = tid - img * (NRT * NSG);
  const int rt  = rem / NSG;
  const int sg  = rem - rt * NSG;
  const int r0  = rt * 3;
  const int jb  = sg * 8;
  const size_t base = (size_t)img * IMGSZ;

  // ct tile: 3 rows x 8 cols at input (r0+rr+3, jb+3+x); mask cols >= 378
  float ct[3][8];
  float t1 = 0.f, t2 = 0.f;
#pragma unroll
  for (int rr = 0; rr < 3; ++rr) {
    const float* tp = target + base + (size_t)(r0 + rr + 3) * 384 + (jb + 3);
    const float* mp = mask   + base + (size_t)(r0 + rr + 3) * 384 + (jb + 3);
#pragma unroll
    for (int x = 0; x < 8; ++x) {
      float v = tp[x] * mp[x];
      v = (jb + x < 378) ? v : 0.f;
      ct[rr][x] = v;
      t1 += v;
      t2 = fmaf(v, v, t2);
    }
  }

  float cc[36];
#pragma unroll
  for (int o = 0; o < 36; ++o) cc[o] = 0.f;
  float tot1 = 0.f, tot2 = 0.f;
  const int ownR = (rt == NRT - 1) ? 8 : 3;   // last row-tile owns rows 375..382

  // pm rows r0..r0+7 (max 382; 16-float col window may spill into next row — in-bounds)
#pragma unroll
  for (int R = 0; R < 8; ++R) {
    const float4* pq = reinterpret_cast<const float4*>(predict + base + (size_t)(r0 + R) * 384 + jb);
    const float4* mq = reinterpret_cast<const float4*>(mask    + base + (size_t)(r0 + R) * 384 + jb);
    float pm[16];
#pragma unroll
    for (int q = 0; q < 4; ++q) {
      float4 a = pq[q];
      float4 b = mq[q];
      pm[4 * q + 0] = a.x * b.x;
      pm[4 * q + 1] = a.y * b.y;
      pm[4 * q + 2] = a.z * b.z;
      pm[4 * q + 3] = a.w * b.w;
    }
    // ownership stats over cols jb..jb+7 (quads 0,1 — always in-row, correct values)
    if (R < ownR) {
#pragma unroll
      for (int x = 0; x < 8; ++x) {
        tot1 += pm[x];
        tot2 = fmaf(pm[x], pm[x], tot2);
      }
    }
    // CC: pm row r0+R serves ct rows rr with u = R-rr in [0,5]
    const int rlo = (R > 5) ? (R - 5) : 0;
    const int rhi = (R < 2) ? R : 2;
#pragma unroll
    for (int rr = rlo; rr <= rhi; ++rr) {
      const int u = R - rr;
#pragma unroll
      for (int v = 0; v < 6; ++v) {
#pragma unroll
        for (int x = 0; x < 8; ++x) {
          cc[u * 6 + v] = fmaf(ct[rr][x], pm[v + x], cc[u * 6 + v]);
        }
      }
    }
  }

  // block reduction: 40 floats
  __shared__ float red[4][NM];
  const int lane = threadIdx.x & 63;
  const int wid  = threadIdx.x >> 6;
#pragma unroll
  for (int o = 0; o < 36; ++o) {
    float a = cc[o];
#pragma unroll
    for (int off = 32; off > 0; off >>= 1) a += __shfl_down(a, off);
    if (lane == 0) red[wid][o] = a;
  }
  {
    float a = t1, b = t2, c = tot1, d = tot2;
#pragma unroll
    for (int off = 32; off > 0; off >>= 1) {
      a += __shfl_down(a, off);
      b += __shfl_down(b, off);
      c += __shfl_down(c, off);
      d += __shfl_down(d, off);
    }
    if (lane == 0) { red[wid][36] = a; red[wid][37] = b; red[wid][38] = c; red[wid][39] = d; }
  }
  __syncthreads();
  if (threadIdx.x < NM) {
    float v = red[0][threadIdx.x] + red[1][threadIdx.x] +
              red[2][threadIdx.x] + red[3][threadIdx.x];
    mpart[blockIdx.x * NM + threadIdx.x] = v;
  }
}

// ---------------- edge kernel: BR/BC/X ingredients per image ----------------
// epart[img][262]: er1[10]@0, er2[10]@10, ec1[11]@20, ec2[11]@31, X1[110]@42, X2[110]@152
__global__ void probav_edge_kernel(const float* __restrict__ predict,
                                   const float* __restrict__ mask,
                                   double* __restrict__ epart) {
  const int img = blockIdx.x;
  const int t = threadIdx.x;
  const size_t base = (size_t)img * IMGSZ;
  __shared__ double sh[506];

  // Phase A: full-row sums, rows {0..4, 378..382}, cols 0..383
  if (t < 250) {
    const int ridx = t / 25, cs = t % 25;
    const int row = (ridx < 5) ? ridx : (373 + ridx);
    const float* pr = predict + base + (size_t)row * 384;
    const float* mr = mask    + base + (size_t)row * 384;
    double e1 = 0.0, e2 = 0.0;
    for (int c = cs; c < 384; c += 25) {
      float v = pr[c] * mr[c];
      e1 += v;
      e2 += (double)v * v;
    }
    sh[ridx * 25 + cs] = e1;
    sh[250 + ridx * 25 + cs] = e2;
  }
  __syncthreads();
  if (t < 20) {
    const int kind = t / 10, ridx = t % 10;
    double s = 0.0;
    for (int k = 0; k < 25; ++k) s += sh[kind * 250 + ridx * 25 + k];
    epart[(size_t)img * NE + kind * 10 + ridx] = s;
  }
  __syncthreads();

  // Phase B: full-col sums, cols {0..4, 378..383}, rows 0..382
  if (t < 253) {
    const int cidx = t / 23, rs = t % 23;
    const int col = (cidx < 5) ? cidx : (373 + cidx);
    double f1 = 0.0, f2 = 0.0;
    for (int r = rs; r < 383; r += 23) {
      float v = predict[base + (size_t)r * 384 + col] * mask[base + (size_t)r * 384 + col];
      f1 += v;
      f2 += (double)v * v;
    }
    sh[cidx * 23 + rs] = f1;
    sh[253 + cidx * 23 + rs] = f2;
  }
  __syncthreads();
  if (t < 22) {
    const int kind = t / 11, cidx = t % 11;
    double s = 0.0;
    for (int k = 0; k < 23; ++k) s += sh[kind * 253 + cidx * 23 + k];
    epart[(size_t)img * NE + 20 + kind * 11 + cidx] = s;
  }

  // Phase C: corner table 10x11 (direct)
  if (t < 110) {
    const int ridx = t / 11, cidx = t % 11;
    const int row = (ridx < 5) ? ridx : (373 + ridx);
    const int col = (cidx < 5) ? cidx : (373 + cidx);
    float v = predict[base + (size_t)row * 384 + col] * mask[base + (size_t)row * 384 + col];
    epart[(size_t)img * NE + 42 + t] = (double)v;
    epart[(size_t)img * NE + 152 + t] = (double)v * v;
  }
}

// ---------------- final kernel: assemble 36 losses, min, score ----------------
__global__ void probav_final_kernel(const float* __restrict__ mpart,
                                    const double* __restrict__ epart,
                                    float* __restrict__ out) {
  __shared__ double sh[480];
  __shared__ double M[NM];
  __shared__ double E[NE];
  __shared__ double loss[36];
  const int t = threadIdx.x;   // 512 threads

  if (t < 480) {
    const int v = t % NM, sl = t / NM;  // 12 slices
    double s = 0.0;
    for (int g = sl; g < NBLK; g += 12) s += (double)mpart[g * NM + v];
    sh[t] = s;
  }
  __syncthreads();
  if (t < NM) {
    double s = 0.0;
    for (int sl = 0; sl < 12; ++sl) s += sh[sl * NM + t];
    M[t] = s;
  }
  __syncthreads();
  if (t < NE) {
    double s = 0.0;
    for (int i = 0; i < NIMG; ++i) s += epart[(size_t)i * NE + t];
    E[t] = s;
  }
  __syncthreads();

  if (t < 36) {
    const int u = t / 6, v = t % 6;
    // bad-row idx: {0..u-1} U {5+u..9};  bad-col idx: {0..v-1} U {5+v..10}
    double br1 = 0, br2 = 0, bc1 = 0, bc2 = 0, x1 = 0, x2 = 0;
    int rset[5], nr = 0;
    for (int j = 0; j < u; ++j) rset[nr++] = j;
    for (int j = 5 + u; j < 10; ++j) rset[nr++] = j;
    int cset[6], nc = 0;
    for (int j = 0; j < v; ++j) cset[nc++] = j;
    for (int j = 5 + v; j < 11; ++j) cset[nc++] = j;
    for (int a = 0; a < nr; ++a) { br1 += E[rset[a]]; br2 += E[10 + rset[a]]; }
    for (int b = 0; b < nc; ++b) { bc1 += E[20 + cset[b]]; bc2 += E[31 + cset[b]]; }
    for (int a = 0; a < nr; ++a)
      for (int b = 0; b < nc; ++b) {
        x1 += E[42 + rset[a] * 11 + cset[b]];
        x2 += E[152 + rset[a] * 11 + cset[b]];
      }
    const double T1 = M[36], T2 = M[37];
    const double W1 = M[38] - br1 - bc1 + x1;
    const double W2 = M[39] - br2 - bc2 + x2;
    const double CCv = M[t];
    const double N = 32.0 * 378.0 * 378.0;
    const double S1 = T1 - W1;
    const double S2 = T2 - 2.0 * CCv + W2;
    loss[t] = S2 / N - (S1 / N) * (S1 / N);
  }
  __syncthreads();
  if (t == 0) {
    double best = loss[0];
    for (int o = 1; o < 36; ++o) best = fmin(best, loss[o]);
    out[0] = (float)(-10.0 * log10(best));
  }
}

extern "C" void kernel_launch(void* const* d_in, const int* in_sizes, int n_in,
                              void* d_out, int out_size, void* d_ws, size_t ws_size,
                              hipStream_t stream) {
  const float* predict = (const float*)d_in[0];
  const float* target  = (const float*)d_in[1];
  const float* mask    = (const float*)d_in[2];
  float* out = (float*)d_out;

  float*  mpart = (float*)d_ws;                              // 756*40*4 = 120960 B
  double* epart = (double*)((char*)d_ws + 756 * NM * 4);     // 32*262*8 =  67072 B

  probav_edge_kernel<<<NIMG, 256, 0, stream>>>(predict, mask, epart);
  probav_cc_kernel<<<NBLK, 256, 0, stream>>>(predict, target, mask, mpart);
  probav_final_kernel<<<1, 512, 0, stream>>>(mpart, epart, out);
}

// Round 3
// 55.791 us; speedup vs baseline: 1.4449x; 1.4449x over previous
//
#include <hip/hip_runtime.h>
#include <hip/hip_bf16.h>
#include <math.h>

// ProbaV cPSNR:  loss(u,v) = E[d^2] - (E[d])^2,  d = ct - pm_window(u,v)
// S1(u,v) = T1 - W1(u,v);  S2(u,v) = T2 - 2*CC(u,v) + W2(u,v)
//   T1,T2   : sum ct, sum ct^2                (ct = target*mask, inner 378x378 @ +3)
//   CC(u,v) : sum ct[r][c] * pm[r+u][c+v]     (pm = predict*mask)
//   W1,W2   : window sums of pm, pm^2 over rows [u,u+378) x cols [v,v+378)
// W = Total - BR(u) - BC(v) + X(u,v)  (inclusion-exclusion over rows 0..382, cols 0..383)

#define NIMG 32
#define IMGSZ (384 * 384)
#define NRT 126              // row tiles (3 ct rows each)
#define NSG 48               // col segments (8 cols)
#define NBLK 756             // cc blocks (NRT*NSG*NIMG/256)
#define NEDGE 64             // edge blocks (2 per image)
#define NM 40                // cc[36], t1, t2, tot1, tot2
#define MSTRIDE 768          // mpart column stride (padded)
#define NE 262               // edge entries per image

// ---------------- fused kernel: cc blocks + edge blocks ----------------
__global__ __launch_bounds__(256, 2) void probav_fused_kernel(
    const float* __restrict__ predict,
    const float* __restrict__ target,
    const float* __restrict__ mask,
    float* __restrict__ mpart /* [NM][MSTRIDE] col-major */,
    double* __restrict__ epart /* [NE][NIMG] */) {

  __shared__ double shbuf[506];
  const int bid = blockIdx.x;
  const int t = threadIdx.x;

  if (bid < NBLK) {
    // ---------------- cc path ----------------
    const int tid = bid * 256 + t;
    const int img = tid / (NRT * NSG);
    const int rem = tid - img * (NRT * NSG);
    const int rt  = rem / NSG;
    const int sg  = rem - rt * NSG;
    const int r0  = rt * 3;
    const int jb  = sg * 8;
    const size_t base = (size_t)img * IMGSZ;

    // ct tile: 3 rows x 8 cols at input (r0+rr+3, jb+3+x); aligned quad loads
    float ct[3][8];
    float t1 = 0.f, t2 = 0.f;
#pragma unroll
    for (int rr = 0; rr < 3; ++rr) {
      const float4* tq = reinterpret_cast<const float4*>(target + base + (size_t)(r0 + rr + 3) * 384 + jb);
      const float4* mq = reinterpret_cast<const float4*>(mask   + base + (size_t)(r0 + rr + 3) * 384 + jb);
      float tv[12], mv[12];
#pragma unroll
      for (int q = 0; q < 3; ++q) {
        float4 a = tq[q];
        float4 b = mq[q];
        tv[4 * q + 0] = a.x; tv[4 * q + 1] = a.y; tv[4 * q + 2] = a.z; tv[4 * q + 3] = a.w;
        mv[4 * q + 0] = b.x; mv[4 * q + 1] = b.y; mv[4 * q + 2] = b.z; mv[4 * q + 3] = b.w;
      }
#pragma unroll
      for (int x = 0; x < 8; ++x) {
        float v = tv[3 + x] * mv[3 + x];
        v = (jb + x < 378) ? v : 0.f;
        ct[rr][x] = v;
        t1 += v;
        t2 = fmaf(v, v, t2);
      }
    }

    float cc[36];
#pragma unroll
    for (int o = 0; o < 36; ++o) cc[o] = 0.f;
    float tot1 = 0.f, tot2 = 0.f;
    const int ownR = (rt == NRT - 1) ? 8 : 3;   // last row-tile owns rows 375..382

#pragma unroll
    for (int R = 0; R < 8; ++R) {
      const float4* pq = reinterpret_cast<const float4*>(predict + base + (size_t)(r0 + R) * 384 + jb);
      const float4* mq = reinterpret_cast<const float4*>(mask    + base + (size_t)(r0 + R) * 384 + jb);
      float pm[16];
#pragma unroll
      for (int q = 0; q < 4; ++q) {
        float4 a = pq[q];
        float4 b = mq[q];
        pm[4 * q + 0] = a.x * b.x;
        pm[4 * q + 1] = a.y * b.y;
        pm[4 * q + 2] = a.z * b.z;
        pm[4 * q + 3] = a.w * b.w;
      }
      if (R < ownR) {
#pragma unroll
        for (int x = 0; x < 8; ++x) {
          tot1 += pm[x];
          tot2 = fmaf(pm[x], pm[x], tot2);
        }
      }
      const int rlo = (R > 5) ? (R - 5) : 0;
      const int rhi = (R < 2) ? R : 2;
#pragma unroll
      for (int rr = rlo; rr <= rhi; ++rr) {
        const int u = R - rr;
#pragma unroll
        for (int v = 0; v < 6; ++v) {
#pragma unroll
          for (int x = 0; x < 8; ++x) {
            cc[u * 6 + v] = fmaf(ct[rr][x], pm[v + x], cc[u * 6 + v]);
          }
        }
      }
    }

    // block reduction: 40 floats -> mpart column-major
    float* red = reinterpret_cast<float*>(shbuf);  // [4][NM]
    const int lane = t & 63;
    const int wid  = t >> 6;
#pragma unroll
    for (int o = 0; o < 36; ++o) {
      float a = cc[o];
#pragma unroll
      for (int off = 32; off > 0; off >>= 1) a += __shfl_down(a, off);
      if (lane == 0) red[wid * NM + o] = a;
    }
    {
      float a = t1, b = t2, c = tot1, d = tot2;
#pragma unroll
      for (int off = 32; off > 0; off >>= 1) {
        a += __shfl_down(a, off);
        b += __shfl_down(b, off);
        c += __shfl_down(c, off);
        d += __shfl_down(d, off);
      }
      if (lane == 0) { red[wid * NM + 36] = a; red[wid * NM + 37] = b; red[wid * NM + 38] = c; red[wid * NM + 39] = d; }
    }
    __syncthreads();
    if (t < NM) {
      float v = red[0 * NM + t] + red[1 * NM + t] + red[2 * NM + t] + red[3 * NM + t];
      mpart[t * MSTRIDE + bid] = v;
    }
  } else {
    // ---------------- edge path ----------------
    const int eb = bid - NBLK;
    const int img = eb >> 1;
    const int slice = eb & 1;
    const size_t base = (size_t)img * IMGSZ;
    double* sh = shbuf;

    if (slice == 0) {
      // Phase A: full-row sums, rows {0..4, 378..382}, cols 0..383
      if (t < 250) {
        const int ridx = t / 25, cs = t % 25;
        const int row = (ridx < 5) ? ridx : (373 + ridx);
        const float* pr = predict + base + (size_t)row * 384;
        const float* mr = mask    + base + (size_t)row * 384;
        double e1 = 0.0, e2 = 0.0;
        for (int c = cs; c < 384; c += 25) {
          float v = pr[c] * mr[c];
          e1 += v;
          e2 += (double)v * v;
        }
        sh[ridx * 25 + cs] = e1;
        sh[250 + ridx * 25 + cs] = e2;
      }
      __syncthreads();
      if (t < 20) {
        const int kind = t / 10, ridx = t % 10;
        double s = 0.0;
        for (int k = 0; k < 25; ++k) s += sh[kind * 250 + ridx * 25 + k];
        epart[(size_t)(kind * 10 + ridx) * NIMG + img] = s;
      }
      // Phase C: corner table 10x11
      if (t < 110) {
        const int ridx = t / 11, cidx = t % 11;
        const int row = (ridx < 5) ? ridx : (373 + ridx);
        const int col = (cidx < 5) ? cidx : (373 + cidx);
        float v = predict[base + (size_t)row * 384 + col] * mask[base + (size_t)row * 384 + col];
        epart[(size_t)(42 + t) * NIMG + img] = (double)v;
        epart[(size_t)(152 + t) * NIMG + img] = (double)v * v;
      }
    } else {
      // Phase B: full-col sums, cols {0..4, 378..383}, rows 0..382
      if (t < 253) {
        const int cidx = t / 23, rs = t % 23;
        const int col = (cidx < 5) ? cidx : (373 + cidx);
        double f1 = 0.0, f2 = 0.0;
        for (int r = rs; r < 383; r += 23) {
          float v = predict[base + (size_t)r * 384 + col] * mask[base + (size_t)r * 384 + col];
          f1 += v;
          f2 += (double)v * v;
        }
        sh[cidx * 23 + rs] = f1;
        sh[253 + cidx * 23 + rs] = f2;
      }
      __syncthreads();
      if (t < 22) {
        const int kind = t / 11, cidx = t % 11;
        double s = 0.0;
        for (int k = 0; k < 23; ++k) s += sh[kind * 253 + cidx * 23 + k];
        epart[(size_t)(20 + kind * 11 + cidx) * NIMG + img] = s;
      }
    }
  }
}

// ---------------- final kernel: assemble 36 losses, min, score ----------------
__global__ void probav_final_kernel(const float* __restrict__ mpart,
                                    const double* __restrict__ epart,
                                    float* __restrict__ out) {
  __shared__ double M[NM];
  __shared__ double E[NE];
  __shared__ double Etmp[524];
  __shared__ double loss[36];
  const int t = threadIdx.x;          // 1024 threads
  const int lane = t & 63;
  const int w = t >> 6;               // 16 waves

  // M: 40 columns of 756 contiguous floats, wave per column
  for (int v = w; v < NM; v += 16) {
    double s = 0.0;
    for (int i = lane; i < NBLK; i += 64) s += (double)mpart[v * MSTRIDE + i];
#pragma unroll
    for (int off = 32; off > 0; off >>= 1) s += __shfl_down(s, off);
    if (lane == 0) M[v] = s;
  }
  // E: 262 entries x 32 contiguous doubles, 2 threads per entry
  if (t < 524) {
    const int e = t >> 1, si = t & 1;
    double s = 0.0;
    for (int i = si * 16; i < si * 16 + 16; ++i) s += epart[(size_t)e * NIMG + i];
    Etmp[t] = s;
  }
  __syncthreads();
  if (t < NE) E[t] = Etmp[2 * t] + Etmp[2 * t + 1];
  __syncthreads();

  if (t < 36) {
    const int u = t / 6, v = t % 6;
    double br1 = 0, br2 = 0, bc1 = 0, bc2 = 0, x1 = 0, x2 = 0;
    int rset[5], nr = 0;
    for (int j = 0; j < u; ++j) rset[nr++] = j;
    for (int j = 5 + u; j < 10; ++j) rset[nr++] = j;
    int cset[6], nc = 0;
    for (int j = 0; j < v; ++j) cset[nc++] = j;
    for (int j = 5 + v; j < 11; ++j) cset[nc++] = j;
    for (int a = 0; a < nr; ++a) { br1 += E[rset[a]]; br2 += E[10 + rset[a]]; }
    for (int b = 0; b < nc; ++b) { bc1 += E[20 + cset[b]]; bc2 += E[31 + cset[b]]; }
    for (int a = 0; a < nr; ++a)
      for (int b = 0; b < nc; ++b) {
        x1 += E[42 + rset[a] * 11 + cset[b]];
        x2 += E[152 + rset[a] * 11 + cset[b]];
      }
    const double T1 = M[36], T2 = M[37];
    const double W1 = M[38] - br1 - bc1 + x1;
    const double W2 = M[39] - br2 - bc2 + x2;
    const double CCv = M[t];
    const double N = 32.0 * 378.0 * 378.0;
    const double S1 = T1 - W1;
    const double S2 = T2 - 2.0 * CCv + W2;
    loss[t] = S2 / N - (S1 / N) * (S1 / N);
  }
  __syncthreads();
  if (t == 0) {
    double best = loss[0];
    for (int o = 1; o < 36; ++o) best = fmin(best, loss[o]);
    out[0] = (float)(-10.0 * log10(best));
  }
}

extern "C" void kernel_launch(void* const* d_in, const int* in_sizes, int n_in,
                              void* d_out, int out_size, void* d_ws, size_t ws_size,
                              hipStream_t stream) {
  const float* predict = (const float*)d_in[0];
  const float* target  = (const float*)d_in[1];
  const float* mask    = (const float*)d_in[2];
  float* out = (float*)d_out;

  float*  mpart = (float*)d_ws;                                  // 40*768*4 = 122880 B
  double* epart = (double*)((char*)d_ws + NM * MSTRIDE * 4);     // 262*32*8 =  67072 B

  probav_fused_kernel<<<NBLK + NEDGE, 256, 0, stream>>>(predict, target, mask, mpart, epart);
  probav_final_kernel<<<1, 1024, 0, stream>>>(mpart, epart, out);
}